// Round 1
// baseline (586.769 us; speedup 1.0000x reference)
//
#include <hip/hip_runtime.h>
#include <hip/hip_bf16.h>

#define E_DIM 4096
#define PS (64 * 4096)   // per-partial GEMM output (floats)

// C(64 x 4096) = A(64 x 4096) @ W(4096 x 4096), K-split partials.
// grid: (N/64, KSPLIT, nWeights). Each block: 64x64 C tile over kchunk K.
__global__ __launch_bounds__(256) void skinny_gemm(
    const float* __restrict__ A,
    const float* __restrict__ W0, const float* __restrict__ W1, const float* __restrict__ W2,
    float* __restrict__ outp, int kchunk)
{
    const int n0 = blockIdx.x << 6;
    const int k0 = blockIdx.y * kchunk;
    const int z  = blockIdx.z;
    const float* __restrict__ W = (z == 0) ? W0 : (z == 1) ? W1 : W2;
    float* __restrict__ out = outp + (size_t)(z * gridDim.y + blockIdx.y) * PS;

    __shared__ float As_t[64][68];  // [k][m]  (transposed x-chunk; pad 68 kills write conflicts)
    __shared__ float Ws[64][68];    // [k][n]

    const int tid = threadIdx.x;
    const int tm = tid >> 4;   // 0..15 -> rows tm*4 .. tm*4+3
    const int tn = tid & 15;   // 0..15 -> cols tn*4 .. tn*4+3

    float acc[4][4] = {{0.f, 0.f, 0.f, 0.f}};

    const int nsub = kchunk >> 6;
    for (int sc = 0; sc < nsub; ++sc) {
        const int kb = k0 + (sc << 6);
        #pragma unroll
        for (int i = 0; i < 4; ++i) {
            const int f = tid + (i << 8);   // float4 slot 0..1023
            const int r = f >> 4;           // 0..63
            const int c = (f & 15) << 2;    // 0..60
            const float4 a4 = *(const float4*)&A[(size_t)r * E_DIM + kb + c];
            As_t[c + 0][r] = a4.x;
            As_t[c + 1][r] = a4.y;
            As_t[c + 2][r] = a4.z;
            As_t[c + 3][r] = a4.w;
            const float4 w4 = *(const float4*)&W[(size_t)(kb + r) * E_DIM + n0 + c];
            *(float4*)&Ws[r][c] = w4;
        }
        __syncthreads();
        #pragma unroll 4
        for (int kk = 0; kk < 64; ++kk) {
            const float4 a4 = *(const float4*)&As_t[kk][tm << 2];
            const float4 w4 = *(const float4*)&Ws[kk][tn << 2];
            const float a[4] = {a4.x, a4.y, a4.z, a4.w};
            const float w[4] = {w4.x, w4.y, w4.z, w4.w};
            #pragma unroll
            for (int mi = 0; mi < 4; ++mi)
                #pragma unroll
                for (int ni = 0; ni < 4; ++ni)
                    acc[mi][ni] += a[mi] * w[ni];
        }
        __syncthreads();
    }
    #pragma unroll
    for (int mi = 0; mi < 4; ++mi) {
        const int m = (tm << 2) + mi;
        *(float4*)&out[(size_t)m * E_DIM + n0 + (tn << 2)] =
            make_float4(acc[mi][0], acc[mi][1], acc[mi][2], acc[mi][3]);
    }
}

// One block per (h, b): sum q/k/v partials, theta_shift, s = qr.kr,
// out[dh] = decay*(prev_kv[dh,:].qr) + s*v[dh], RMS-norm over dh -> normed.
__global__ __launch_bounds__(256) void retention(
    const float* __restrict__ qkvp, const float* __restrict__ prev_kv,
    const float* __restrict__ decay, const float* __restrict__ sinp,
    const float* __restrict__ cosp, float* __restrict__ normed)
{
    const int h = blockIdx.x;          // 16
    const int b = blockIdx.y;          // 64
    const int t = threadIdx.x;         // 256 (dk for phase 1, dh for phase 3)
    const int lane = t & 63, wave = t >> 6;
    const int col = (h << 8) + t;

    // --- gather q,k,v (sum 4 K-split partials each) ---
    float q = 0.f, k = 0.f, v = 0.f;
    #pragma unroll
    for (int p = 0; p < 4; ++p) {
        const size_t base = (size_t)p * PS + (size_t)b * E_DIM + col;
        q += qkvp[base];
        k += qkvp[4 * (size_t)PS + base];
        v += qkvp[8 * (size_t)PS + base];
    }

    // --- theta_shift: rot[t] = (t even ? -x[t+1] : x[t-1]) ---
    const float sc = sinp[t], cc = cosp[t];
    const float qp = __shfl_xor(q, 1);
    const float kp = __shfl_xor(k, 1);
    const float sgn = (t & 1) ? 1.0f : -1.0f;
    const float qr = q * cc + sgn * qp * sc;
    const float kr = k * cc + sgn * kp * sc;

    __shared__ float qr_s[256];
    __shared__ float outv[256];
    __shared__ float red_s[4];
    __shared__ float red_q[4];

    float prod = qr * kr;
    #pragma unroll
    for (int o = 32; o; o >>= 1) prod += __shfl_xor(prod, o);
    qr_s[t] = qr;
    if (lane == 0) red_s[wave] = prod;
    __syncthreads();

    const float s = red_s[0] + red_s[1] + red_s[2] + red_s[3];
    const float4 qr4 = *(const float4*)&qr_s[lane << 2];

    // --- matvec: wave w handles rows [w*64, w*64+64); one 1KB row per wave-load ---
    const float* __restrict__ M = prev_kv + ((size_t)((b << 4) + h) << 16);
    #pragma unroll 4
    for (int r = 0; r < 64; ++r) {
        const int dh = (wave << 6) + r;
        const float4 m4 = *(const float4*)&M[(size_t)dh * 256 + (lane << 2)];
        float d = m4.x * qr4.x + m4.y * qr4.y + m4.z * qr4.z + m4.w * qr4.w;
        #pragma unroll
        for (int o = 32; o; o >>= 1) d += __shfl_xor(d, o);
        if (lane == 0) outv[dh] = d;
    }
    __syncthreads();

    // --- combine + RMS norm over the 256 dh of this (b,h) ---
    const float o = decay[h] * outv[t] + s * v;
    float ss = o * o;
    #pragma unroll
    for (int off = 32; off; off >>= 1) ss += __shfl_xor(ss, off);
    if (lane == 0) red_q[wave] = ss;
    __syncthreads();
    const float sumsq = red_q[0] + red_q[1] + red_q[2] + red_q[3];
    const float scale = rsqrtf(sumsq * (1.0f / 256.0f) + 1e-6f);
    normed[(size_t)b * E_DIM + col] = o * scale;
}

// d_out = sum of 8 Wo-GEMM partials (float4 granularity, 65536 float4s).
__global__ __launch_bounds__(256) void sum8(
    const float* __restrict__ wop, float* __restrict__ out)
{
    const int i = blockIdx.x * 256 + threadIdx.x;   // 0..65535
    const float4* __restrict__ p = (const float4*)wop;
    float4 s = p[i];
    #pragma unroll
    for (int j = 1; j < 8; ++j) {
        const float4 u = p[(size_t)j * 65536 + i];
        s.x += u.x; s.y += u.y; s.z += u.z; s.w += u.w;
    }
    ((float4*)out)[i] = s;
}

extern "C" void kernel_launch(void* const* d_in, const int* in_sizes, int n_in,
                              void* d_out, int out_size, void* d_ws, size_t ws_size,
                              hipStream_t stream)
{
    const float* x       = (const float*)d_in[0];
    const float* sinp    = (const float*)d_in[1];
    const float* cosp    = (const float*)d_in[2];
    const float* decay   = (const float*)d_in[3];
    const float* prev_kv = (const float*)d_in[4];
    const float* Wq      = (const float*)d_in[5];
    const float* Wk      = (const float*)d_in[6];
    const float* Wv      = (const float*)d_in[7];
    const float* Wo      = (const float*)d_in[8];
    float* out = (float*)d_out;

    float* ws     = (float*)d_ws;
    float* qkvp   = ws;                        // 3 weights * 4 partials * 262144
    float* normed = ws + (size_t)12 * PS;      // 262144
    float* wop    = ws + (size_t)13 * PS;      // 8 partials * 262144

    // q,k,v projections: grid (N/64, ksplit=4, 3 weights), kchunk=1024
    dim3 g1(64, 4, 3);
    skinny_gemm<<<g1, 256, 0, stream>>>(x, Wq, Wk, Wv, qkvp, 1024);

    // retention + RMS norm: one block per (h, b)
    dim3 g2(16, 64, 1);
    retention<<<g2, 256, 0, stream>>>(qkvp, prev_kv, decay, sinp, cosp, normed);

    // output projection: grid (N/64, ksplit=8, 1), kchunk=512
    dim3 g3(64, 8, 1);
    skinny_gemm<<<g3, 256, 0, stream>>>(normed, Wo, Wo, Wo, wop, 512);

    // reduce 8 partials into d_out
    sum8<<<256, 256, 0, stream>>>(wop, out);
}